// Round 8
// baseline (1089.986 us; speedup 1.0000x reference)
//
#include <hip/hip_runtime.h>
#include <hip/hip_bf16.h>
#include <stdint.h>

#define N_ENC 2048
#define BATCH 32
#define M_TOT (N_ENC * BATCH)   // 65536 rows (s*32+b)
#define K_DIM 1024
#define N_DIM 1024
#define BK 64
#define NT (K_DIM / BK)          // 16 K-tiles

typedef __attribute__((ext_vector_type(4))) float f32x4;
typedef __attribute__((ext_vector_type(8))) short short8;

__device__ __forceinline__ unsigned int pack_bf16x2(float lo, float hi) {
  unsigned int a = __float_as_uint(lo);
  unsigned int b = __float_as_uint(hi);
  a = (a + 0x7fffu + ((a >> 16) & 1u)) >> 16;          // RNE to bf16, low half
  b = (b + 0x7fffu + ((b >> 16) & 1u)) & 0xffff0000u;  // RNE to bf16, high half
  return a | b;
}

__device__ __forceinline__ float bf2f(unsigned short u) {
  return __uint_as_float((unsigned int)u << 16);
}

__device__ __forceinline__ float tanh_fast(float x) {
  float e = __expf(2.0f * x);
  return 1.0f - 2.0f / (e + 1.0f);
}

// ---- f32 -> bf16 bulk convert, grid-stride ----
__global__ void k_convert_bf16(const float* __restrict__ src,
                               unsigned short* __restrict__ dst, int n8) {
  for (int i = blockIdx.x * 256 + threadIdx.x; i < n8; i += gridDim.x * 256) {
    const float* p = src + (size_t)i * 8;
    f32x4 v0 = *(const f32x4*)p;
    f32x4 v1 = *(const f32x4*)(p + 4);
    uint4 o;
    o.x = pack_bf16x2(v0.x, v0.y);
    o.y = pack_bf16x2(v0.z, v0.w);
    o.z = pack_bf16x2(v1.x, v1.y);
    o.w = pack_bf16x2(v1.z, v1.w);
    *(uint4*)(dst + (size_t)i * 8) = o;
  }
}

// ---- proj_dec[b][h] = sum_d dec[b][d] * w_dec[h][d] ----
__global__ void k_proj_dec(const float* __restrict__ dec,
                           const float* __restrict__ w_dec,
                           float* __restrict__ proj) {
  int t = threadIdx.x;
  int hh = t & 7, b = t >> 3;
  int h = blockIdx.x * 8 + hh;
  const float* wr = w_dec + (size_t)h * K_DIM;
  const float* dr = dec + (size_t)b * K_DIM;
  float acc = 0.f;
  for (int d = 0; d < K_DIM; d += 4) {
    f32x4 wv = *(const f32x4*)(wr + d);
    f32x4 dv = *(const f32x4*)(dr + d);
    acc = fmaf(wv.x, dv.x, acc);
    acc = fmaf(wv.y, dv.y, acc);
    acc = fmaf(wv.z, dv.z, acc);
    acc = fmaf(wv.w, dv.w, acc);
  }
  proj[b * N_DIM + h] = acc;
}

// ---- m97-structure fused GEMM: 128x128 tile, BK=64, 4 waves, single-buffer
// 32 KiB LDS -> 5 blocks/CU. TLP (not intra-wave pipelining) hides the
// per-tile vmcnt drain. logits[m] += sum_h tanh(A.We + pdec)*wout.
__global__ __launch_bounds__(256, 5) void k_gemm128(
    const unsigned short* __restrict__ Abf,  // enc bf16 [65536][1024]
    const unsigned short* __restrict__ B,    // w_enc bf16 [1024][1024]
    const float* __restrict__ pdec,          // [32][1024]
    const float* __restrict__ wout,          // [1024]
    float* __restrict__ logits)              // [65536] (pre-zeroed)
{
  __shared__ __align__(16) unsigned short Asm[128 * BK];  // 16 KiB, XOR-swizzled
  __shared__ __align__(16) unsigned short Bsm[128 * BK];  // 16 KiB, XOR-swizzled

  // XCD-aware bijective swizzle: 8 n-siblings of one A-tile -> same XCD.
  const int nwg = (M_TOT / 128) * (N_DIM / 128);   // 4096, %8==0
  const int cpx = nwg / 8;                         // 512
  const int bid = ((int)blockIdx.x % 8) * cpx + (int)blockIdx.x / 8;
  const int nt = bid & 7;        // n fastest: 8 siblings share an A tile
  const int mt = bid >> 3;
  const int m0 = mt * 128, n0 = nt * 128;
  const int t = threadIdx.x;
  const int lane = t & 63;
  const int w = t >> 6;
  const int wm = w >> 1, wn = w & 1;     // 2x2 waves of 64x64
  const int g = lane >> 4, c16 = lane & 15;

  f32x4 acc[4][4];
#pragma unroll
  for (int a = 0; a < 4; ++a)
#pragma unroll
    for (int b = 0; b < 4; ++b) acc[a][b] = {0.f, 0.f, 0.f, 0.f};

  // per-thread staging source pointers (pre-swizzled), 4 A items + 4 B items
  const unsigned short* gA[4];
  const unsigned short* gB[4];
#pragma unroll
  for (int r = 0; r < 4; ++r) {
    int item = r * 256 + t;            // 1024 items of 16B per matrix
    int row = item >> 3;
    int sub = (item & 7) ^ (row & 7);  // inverse swizzle on SOURCE
    gA[r] = Abf + (size_t)(m0 + row) * K_DIM + sub * 8;
    gB[r] = B   + (size_t)(n0 + row) * K_DIM + sub * 8;
  }

  for (int kt = 0; kt < NT; ++kt) {
    // -- stage A+B via global_load_lds (linear LDS dest = swizzled layout) --
#pragma unroll
    for (int r = 0; r < 4; ++r) {
      __builtin_amdgcn_global_load_lds(
          (const __attribute__((address_space(1))) void*)gA[r],
          (__attribute__((address_space(3))) void*)&Asm[(r * 256 + t) * 8],
          16, 0, 0);
      gA[r] += BK;
      __builtin_amdgcn_global_load_lds(
          (const __attribute__((address_space(1))) void*)gB[r],
          (__attribute__((address_space(3))) void*)&Bsm[(r * 256 + t) * 8],
          16, 0, 0);
      gB[r] += BK;
    }
    __syncthreads();   // drains vmcnt -> staged tile visible to all waves
    // -- compute: 2 k-passes of 16 MFMA --
#pragma unroll
    for (int ks = 0; ks < 2; ++ks) {
      const int sub = ks * 4 + g;
      short8 af[4], bfr[4];
#pragma unroll
      for (int a = 0; a < 4; ++a) {
        int row = wm * 64 + a * 16 + c16;
        af[a] = *(const short8*)&Asm[row * 64 + ((sub ^ (row & 7)) * 8)];
      }
#pragma unroll
      for (int b = 0; b < 4; ++b) {
        int row = wn * 64 + b * 16 + c16;
        bfr[b] = *(const short8*)&Bsm[row * 64 + ((sub ^ (row & 7)) * 8)];
      }
#pragma unroll
      for (int a = 0; a < 4; ++a)
#pragma unroll
        for (int b = 0; b < 4; ++b)
          acc[a][b] = __builtin_amdgcn_mfma_f32_16x16x32_bf16(
              af[a], bfr[b], acc[a][b], 0, 0, 0);
    }
    __syncthreads();   // all reads done before next stage overwrites
  }

  // -- epilogue: tanh(acc + pdec) . wout, shfl-reduce 16 cols, atomic per row --
#pragma unroll
  for (int a = 0; a < 4; ++a) {
    float psum[4] = {0.f, 0.f, 0.f, 0.f};
#pragma unroll
    for (int b = 0; b < 4; ++b) {
      const int col = n0 + wn * 64 + b * 16 + c16;
      const float wo = wout[col];
#pragma unroll
      for (int j = 0; j < 4; ++j) {
        const int rl = wm * 64 + a * 16 + g * 4 + j;  // C/D: col=lane&15, row=(lane>>4)*4+j
        const int bidx = rl & 31;                     // m0 multiple of 32
        float v = acc[a][b][j] + pdec[bidx * N_DIM + col];
        psum[j] = fmaf(tanh_fast(v), wo, psum[j]);
      }
    }
#pragma unroll
    for (int j = 0; j < 4; ++j) {
      float p = psum[j];
      p += __shfl_xor(p, 1);
      p += __shfl_xor(p, 2);
      p += __shfl_xor(p, 4);
      p += __shfl_xor(p, 8);
      if (c16 == 0)
        atomicAdd(&logits[m0 + wm * 64 + a * 16 + g * 4 + j], p);
    }
  }
}

// ---- fallback f32-A 128^2 GEMM (used only if ws too small for enc_bf) ----
__global__ __launch_bounds__(256) void k_gemm_f32(
    const float* __restrict__ A,
    const unsigned short* __restrict__ B,
    const float* __restrict__ pdec,
    const float* __restrict__ wout,
    float* __restrict__ logits)
{
  __shared__ __align__(16) unsigned short Asm[128 * BK];
  __shared__ __align__(16) unsigned short Bsm[128 * BK];
  const int bid = blockIdx.x;
  const int nt = bid & 7;
  const int mt = bid >> 3;
  const int m0 = mt * 128, n0 = nt * 128;
  const int t = threadIdx.x;
  const int lane = t & 63;
  const int w = t >> 6;
  const int wm = w >> 1, wn = w & 1;
  const int g = lane >> 4, c16 = lane & 15;

  f32x4 acc[4][4];
#pragma unroll
  for (int a = 0; a < 4; ++a)
#pragma unroll
    for (int b = 0; b < 4; ++b) acc[a][b] = {0.f, 0.f, 0.f, 0.f};

  for (int kt = 0; kt < NT; ++kt) {
    const int k0 = kt * BK;
#pragma unroll
    for (int i = 0; i < 4; ++i) {
      int item = i * 256 + t;
      int row = item >> 3;
      int sub = item & 7;
      const float* src = A + (size_t)(m0 + row) * K_DIM + k0 + sub * 8;
      f32x4 v0 = *(const f32x4*)src;
      f32x4 v1 = *(const f32x4*)(src + 4);
      uint4 o;
      o.x = pack_bf16x2(v0.x, v0.y);
      o.y = pack_bf16x2(v0.z, v0.w);
      o.z = pack_bf16x2(v1.x, v1.y);
      o.w = pack_bf16x2(v1.z, v1.w);
      int chunk = sub ^ (row & 7);
      *(uint4*)&Asm[row * 64 + chunk * 8] = o;
    }
#pragma unroll
    for (int j = 0; j < 4; ++j) {
      int chunkid = w * 4 + j;
      int item = chunkid * 64 + lane;
      int row = item >> 3;
      int sub = (item & 7) ^ (row & 7);
      const unsigned short* gp = B + (size_t)(n0 + row) * K_DIM + k0 + sub * 8;
      __builtin_amdgcn_global_load_lds(
          (const __attribute__((address_space(1))) void*)gp,
          (__attribute__((address_space(3))) void*)&Bsm[chunkid * 512],
          16, 0, 0);
    }
    __syncthreads();
#pragma unroll
    for (int ks = 0; ks < 2; ++ks) {
      const int sub = ks * 4 + g;
      short8 af[4], bfr[4];
#pragma unroll
      for (int a = 0; a < 4; ++a) {
        int row = wm * 64 + a * 16 + c16;
        af[a] = *(const short8*)&Asm[row * 64 + ((sub ^ (row & 7)) * 8)];
      }
#pragma unroll
      for (int b = 0; b < 4; ++b) {
        int row = wn * 64 + b * 16 + c16;
        bfr[b] = *(const short8*)&Bsm[row * 64 + ((sub ^ (row & 7)) * 8)];
      }
#pragma unroll
      for (int a = 0; a < 4; ++a)
#pragma unroll
        for (int b = 0; b < 4; ++b)
          acc[a][b] = __builtin_amdgcn_mfma_f32_16x16x32_bf16(
              af[a], bfr[b], acc[a][b], 0, 0, 0);
    }
    __syncthreads();
  }
#pragma unroll
  for (int a = 0; a < 4; ++a) {
    float psum[4] = {0.f, 0.f, 0.f, 0.f};
#pragma unroll
    for (int b = 0; b < 4; ++b) {
      const int col = n0 + wn * 64 + b * 16 + c16;
      const float wo = wout[col];
#pragma unroll
      for (int j = 0; j < 4; ++j) {
        const int rl = wm * 64 + a * 16 + g * 4 + j;
        const int bidx = rl & 31;
        float v = acc[a][b][j] + pdec[bidx * N_DIM + col];
        psum[j] = fmaf(tanh_fast(v), wo, psum[j]);
      }
    }
#pragma unroll
    for (int j = 0; j < 4; ++j) {
      float p = psum[j];
      p += __shfl_xor(p, 1);
      p += __shfl_xor(p, 2);
      p += __shfl_xor(p, 4);
      p += __shfl_xor(p, 8);
      if (c16 == 0)
        atomicAdd(&logits[m0 + wm * 64 + a * 16 + g * 4 + j], p);
    }
  }
}

// ---- masked softmax over s per batch column; mask dtype auto-detected ----
__global__ void k_softmax(const float* __restrict__ logits,
                          const void* __restrict__ maskp,
                          float* __restrict__ weights) {
  const int b = blockIdx.x;
  const int t = threadIdx.x;
  const int lane = t & 63, wid = t >> 6;
  __shared__ float red[8];
  __shared__ int modeflags[2];

  if (t < 2) modeflags[t] = 0;
  __syncthreads();
  unsigned int w0 = ((const unsigned int*)maskp)[t];
  if (w0 == 0x3f800000u) modeflags[1] = 1;
  else if (w0 > 1u) modeflags[0] = 1;
  __syncthreads();
  const int mode = modeflags[1] ? 2 : (modeflags[0] ? 1 : 0);

  float v[8];
  float mx = -3.0e38f;
#pragma unroll
  for (int i = 0; i < 8; ++i) {
    int idx = (t + i * 256) * BATCH + b;
    float l = logits[idx];
    int mk;
    if (mode == 0) mk = ((const int*)maskp)[idx];
    else if (mode == 1) mk = ((const unsigned char*)maskp)[idx];
    else mk = (((const float*)maskp)[idx] != 0.f);
    l = mk ? l : -2.0e9f;
    v[i] = l;
    mx = fmaxf(mx, l);
  }
#pragma unroll
  for (int off = 1; off < 64; off <<= 1) mx = fmaxf(mx, __shfl_xor(mx, off));
  if (lane == 0) red[wid] = mx;
  __syncthreads();
  mx = fmaxf(fmaxf(red[0], red[1]), fmaxf(red[2], red[3]));

  float sum = 0.f;
#pragma unroll
  for (int i = 0; i < 8; ++i) {
    float e = __expf(v[i] - mx);
    v[i] = e;
    sum += e;
  }
#pragma unroll
  for (int off = 1; off < 64; off <<= 1) sum += __shfl_xor(sum, off);
  if (lane == 0) red[4 + wid] = sum;
  __syncthreads();
  sum = red[4] + red[5] + red[6] + red[7];
  float inv = 1.0f / sum;
#pragma unroll
  for (int i = 0; i < 8; ++i)
    weights[(t + i * 256) * BATCH + b] = v[i] * inv;
}

// ---- attn_response[b][e] = sum_s w[s][b] * enc_bf[s][b][e] ----
__global__ void k_response_bf(const unsigned short* __restrict__ enc_bf,
                              const float* __restrict__ weights,
                              float* __restrict__ out) {
  const int b = blockIdx.x & 31;
  const int ch = blockIdx.x >> 5;
  const int e = threadIdx.x * 4;
  float a0 = 0.f, a1 = 0.f, a2 = 0.f, a3 = 0.f;
  const int s0 = ch * (N_ENC / 16);
  for (int s = s0; s < s0 + N_ENC / 16; ++s) {
    float wv = weights[s * BATCH + b];
    ushort4 x = *(const ushort4*)(enc_bf + ((size_t)s * BATCH + b) * K_DIM + e);
    a0 = fmaf(wv, bf2f(x.x), a0);
    a1 = fmaf(wv, bf2f(x.y), a1);
    a2 = fmaf(wv, bf2f(x.z), a2);
    a3 = fmaf(wv, bf2f(x.w), a3);
  }
  atomicAdd(&out[b * K_DIM + e + 0], a0);
  atomicAdd(&out[b * K_DIM + e + 1], a1);
  atomicAdd(&out[b * K_DIM + e + 2], a2);
  atomicAdd(&out[b * K_DIM + e + 3], a3);
}

__global__ void k_response(const float* __restrict__ enc,
                           const float* __restrict__ weights,
                           float* __restrict__ out) {
  const int b = blockIdx.x & 31;
  const int ch = blockIdx.x >> 5;
  const int e = threadIdx.x * 4;
  float a0 = 0.f, a1 = 0.f, a2 = 0.f, a3 = 0.f;
  const int s0 = ch * (N_ENC / 16);
  for (int s = s0; s < s0 + N_ENC / 16; ++s) {
    float wv = weights[s * BATCH + b];
    f32x4 x = *(const f32x4*)(enc + ((size_t)s * BATCH + b) * K_DIM + e);
    a0 = fmaf(wv, x.x, a0);
    a1 = fmaf(wv, x.y, a1);
    a2 = fmaf(wv, x.z, a2);
    a3 = fmaf(wv, x.w, a3);
  }
  atomicAdd(&out[b * K_DIM + e + 0], a0);
  atomicAdd(&out[b * K_DIM + e + 1], a1);
  atomicAdd(&out[b * K_DIM + e + 2], a2);
  atomicAdd(&out[b * K_DIM + e + 3], a3);
}

extern "C" void kernel_launch(void* const* d_in, const int* in_sizes, int n_in,
                              void* d_out, int out_size, void* d_ws, size_t ws_size,
                              hipStream_t stream) {
  const float* enc   = (const float*)d_in[0];
  const void*  mask  = d_in[1];
  const float* dec   = (const float*)d_in[2];
  const float* w_enc = (const float*)d_in[3];
  const float* w_dec = (const float*)d_in[4];
  const float* w_out = (const float*)d_in[5];

  float* out_resp = (float*)d_out;                 // [32*1024]
  float* out_w    = out_resp + BATCH * K_DIM;      // [2048*32]

  const size_t enc_bf_bytes = (size_t)M_TOT * K_DIM * 2;       // 128 MiB
  const size_t need = enc_bf_bytes + 2 * 1024 * 1024 + 128 * 1024 + 256 * 1024;
  const bool pre = ws_size >= need;

  char* wsB = (char*)d_ws;
  unsigned short* enc_bf   = (unsigned short*)wsB;
  size_t off = pre ? enc_bf_bytes : 0;
  unsigned short* w_enc_bf = (unsigned short*)(wsB + off);     off += 2 * 1024 * 1024;
  float* pdec   = (float*)(wsB + off);                         off += 128 * 1024;
  float* logits = (float*)(wsB + off);

  hipMemsetAsync(logits, 0, (size_t)M_TOT * sizeof(float), stream);
  hipMemsetAsync(out_resp, 0, (size_t)BATCH * K_DIM * sizeof(float), stream);

  k_convert_bf16<<<512, 256, 0, stream>>>(w_enc, w_enc_bf, N_DIM * K_DIM / 8);
  k_proj_dec<<<N_DIM / 8, 256, 0, stream>>>(dec, w_dec, pdec);

  if (pre) {
    k_convert_bf16<<<2048, 256, 0, stream>>>(enc, enc_bf, M_TOT * (K_DIM / 8));
    k_gemm128<<<(M_TOT / 128) * (N_DIM / 128), 256, 0, stream>>>(
        enc_bf, w_enc_bf, pdec, w_out, logits);
  } else {
    k_gemm_f32<<<(M_TOT / 128) * (N_DIM / 128), 256, 0, stream>>>(
        enc, w_enc_bf, pdec, w_out, logits);
  }

  k_softmax<<<BATCH, 256, 0, stream>>>(logits, mask, out_w);

  if (pre) {
    k_response_bf<<<BATCH * 16, 256, 0, stream>>>(enc_bf, out_w, out_resp);
  } else {
    k_response<<<BATCH * 16, 256, 0, stream>>>(enc, out_w, out_resp);
  }
}

// Round 9
// 341.976 us; speedup vs baseline: 3.1873x; 3.1873x over previous
//
#include <hip/hip_runtime.h>
#include <hip/hip_bf16.h>
#include <stdint.h>

#define N_ENC 2048
#define BATCH 32
#define M_TOT (N_ENC * BATCH)   // 65536 rows (s*32+b)
#define K_DIM 1024
#define N_DIM 1024
#define BK 64
#define NT (K_DIM / BK)          // 16 K-tiles

typedef __attribute__((ext_vector_type(4))) float f32x4;
typedef __attribute__((ext_vector_type(8))) short short8;

__device__ __forceinline__ unsigned int pack_bf16x2(float lo, float hi) {
  unsigned int a = __float_as_uint(lo);
  unsigned int b = __float_as_uint(hi);
  a = (a + 0x7fffu + ((a >> 16) & 1u)) >> 16;          // RNE to bf16, low half
  b = (b + 0x7fffu + ((b >> 16) & 1u)) & 0xffff0000u;  // RNE to bf16, high half
  return a | b;
}

__device__ __forceinline__ float bf2f(unsigned short u) {
  return __uint_as_float((unsigned int)u << 16);
}

__device__ __forceinline__ float tanh_fast(float x) {
  float e = __expf(2.0f * x);
  return 1.0f - 2.0f / (e + 1.0f);
}

// ---- f32 -> bf16 bulk convert, grid-stride ----
__global__ void k_convert_bf16(const float* __restrict__ src,
                               unsigned short* __restrict__ dst, int n8) {
  for (int i = blockIdx.x * 256 + threadIdx.x; i < n8; i += gridDim.x * 256) {
    const float* p = src + (size_t)i * 8;
    f32x4 v0 = *(const f32x4*)p;
    f32x4 v1 = *(const f32x4*)(p + 4);
    uint4 o;
    o.x = pack_bf16x2(v0.x, v0.y);
    o.y = pack_bf16x2(v0.z, v0.w);
    o.z = pack_bf16x2(v1.x, v1.y);
    o.w = pack_bf16x2(v1.z, v1.w);
    *(uint4*)(dst + (size_t)i * 8) = o;
  }
}

// ---- proj_dec[b][h] = sum_d dec[b][d] * w_dec[h][d] ----
__global__ void k_proj_dec(const float* __restrict__ dec,
                           const float* __restrict__ w_dec,
                           float* __restrict__ proj) {
  int t = threadIdx.x;
  int hh = t & 7, b = t >> 3;
  int h = blockIdx.x * 8 + hh;
  const float* wr = w_dec + (size_t)h * K_DIM;
  const float* dr = dec + (size_t)b * K_DIM;
  float acc = 0.f;
  for (int d = 0; d < K_DIM; d += 4) {
    f32x4 wv = *(const f32x4*)(wr + d);
    f32x4 dv = *(const f32x4*)(dr + d);
    acc = fmaf(wv.x, dv.x, acc);
    acc = fmaf(wv.y, dv.y, acc);
    acc = fmaf(wv.z, dv.z, acc);
    acc = fmaf(wv.w, dv.w, acc);
  }
  proj[b * N_DIM + h] = acc;
}

// ---- m97-structure fused GEMM: 128x128 tile, BK=64, 4 waves, single-buffer
// 32 KiB LDS. __launch_bounds__(256,3): m97's real operating point (~164 VGPR,
// 3 blocks/CU). R8's (256,5) capped VGPR at ~96 -> acc spilled to scratch
// (VGPR=48, 1.5 GB scratch writes, 5.8% MfmaUtil).
__global__ __launch_bounds__(256, 3) void k_gemm128(
    const unsigned short* __restrict__ Abf,  // enc bf16 [65536][1024]
    const unsigned short* __restrict__ B,    // w_enc bf16 [1024][1024]
    const float* __restrict__ pdec,          // [32][1024]
    const float* __restrict__ wout,          // [1024]
    float* __restrict__ logits)              // [65536] (pre-zeroed)
{
  __shared__ __align__(16) unsigned short Asm[128 * BK];  // 16 KiB, XOR-swizzled
  __shared__ __align__(16) unsigned short Bsm[128 * BK];  // 16 KiB, XOR-swizzled

  // XCD-aware bijective swizzle: 8 n-siblings of one A-tile -> same XCD.
  const int nwg = (M_TOT / 128) * (N_DIM / 128);   // 4096, %8==0
  const int cpx = nwg / 8;                         // 512
  const int bid = ((int)blockIdx.x % 8) * cpx + (int)blockIdx.x / 8;
  const int nt = bid & 7;        // n fastest: 8 siblings share an A tile
  const int mt = bid >> 3;
  const int m0 = mt * 128, n0 = nt * 128;
  const int t = threadIdx.x;
  const int lane = t & 63;
  const int w = t >> 6;
  const int wm = w >> 1, wn = w & 1;     // 2x2 waves of 64x64
  const int g = lane >> 4, c16 = lane & 15;

  f32x4 acc[4][4];
#pragma unroll
  for (int a = 0; a < 4; ++a)
#pragma unroll
    for (int b = 0; b < 4; ++b) acc[a][b] = {0.f, 0.f, 0.f, 0.f};

  // per-thread staging source pointers (pre-swizzled), 4 A items + 4 B items
  const unsigned short* gA[4];
  const unsigned short* gB[4];
#pragma unroll
  for (int r = 0; r < 4; ++r) {
    int item = r * 256 + t;            // 1024 items of 16B per matrix
    int row = item >> 3;
    int sub = (item & 7) ^ (row & 7);  // inverse swizzle on SOURCE
    gA[r] = Abf + (size_t)(m0 + row) * K_DIM + sub * 8;
    gB[r] = B   + (size_t)(n0 + row) * K_DIM + sub * 8;
  }

  for (int kt = 0; kt < NT; ++kt) {
    // -- stage A+B via global_load_lds (linear LDS dest = swizzled layout) --
#pragma unroll
    for (int r = 0; r < 4; ++r) {
      __builtin_amdgcn_global_load_lds(
          (const __attribute__((address_space(1))) void*)gA[r],
          (__attribute__((address_space(3))) void*)&Asm[(r * 256 + t) * 8],
          16, 0, 0);
      gA[r] += BK;
      __builtin_amdgcn_global_load_lds(
          (const __attribute__((address_space(1))) void*)gB[r],
          (__attribute__((address_space(3))) void*)&Bsm[(r * 256 + t) * 8],
          16, 0, 0);
      gB[r] += BK;
    }
    __syncthreads();   // drains vmcnt -> staged tile visible to all waves
    // -- compute: 2 k-passes of 16 MFMA --
#pragma unroll
    for (int ks = 0; ks < 2; ++ks) {
      const int sub = ks * 4 + g;
      short8 af[4], bfr[4];
#pragma unroll
      for (int a = 0; a < 4; ++a) {
        int row = wm * 64 + a * 16 + c16;
        af[a] = *(const short8*)&Asm[row * 64 + ((sub ^ (row & 7)) * 8)];
      }
#pragma unroll
      for (int b = 0; b < 4; ++b) {
        int row = wn * 64 + b * 16 + c16;
        bfr[b] = *(const short8*)&Bsm[row * 64 + ((sub ^ (row & 7)) * 8)];
      }
#pragma unroll
      for (int a = 0; a < 4; ++a)
#pragma unroll
        for (int b = 0; b < 4; ++b)
          acc[a][b] = __builtin_amdgcn_mfma_f32_16x16x32_bf16(
              af[a], bfr[b], acc[a][b], 0, 0, 0);
    }
    __syncthreads();   // all reads done before next stage overwrites
  }

  // -- epilogue: tanh(acc + pdec) . wout, shfl-reduce 16 cols, atomic per row --
#pragma unroll
  for (int a = 0; a < 4; ++a) {
    float psum[4] = {0.f, 0.f, 0.f, 0.f};
#pragma unroll
    for (int b = 0; b < 4; ++b) {
      const int col = n0 + wn * 64 + b * 16 + c16;
      const float wo = wout[col];
#pragma unroll
      for (int j = 0; j < 4; ++j) {
        const int rl = wm * 64 + a * 16 + g * 4 + j;  // C/D: col=lane&15, row=(lane>>4)*4+j
        const int bidx = rl & 31;                     // m0 multiple of 32
        float v = acc[a][b][j] + pdec[bidx * N_DIM + col];
        psum[j] = fmaf(tanh_fast(v), wo, psum[j]);
      }
    }
#pragma unroll
    for (int j = 0; j < 4; ++j) {
      float p = psum[j];
      p += __shfl_xor(p, 1);
      p += __shfl_xor(p, 2);
      p += __shfl_xor(p, 4);
      p += __shfl_xor(p, 8);
      if (c16 == 0)
        atomicAdd(&logits[m0 + wm * 64 + a * 16 + g * 4 + j], p);
    }
  }
}

// ---- fallback f32-A 128^2 GEMM (used only if ws too small for enc_bf) ----
__global__ __launch_bounds__(256) void k_gemm_f32(
    const float* __restrict__ A,
    const unsigned short* __restrict__ B,
    const float* __restrict__ pdec,
    const float* __restrict__ wout,
    float* __restrict__ logits)
{
  __shared__ __align__(16) unsigned short Asm[128 * BK];
  __shared__ __align__(16) unsigned short Bsm[128 * BK];
  const int bid = blockIdx.x;
  const int nt = bid & 7;
  const int mt = bid >> 3;
  const int m0 = mt * 128, n0 = nt * 128;
  const int t = threadIdx.x;
  const int lane = t & 63;
  const int w = t >> 6;
  const int wm = w >> 1, wn = w & 1;
  const int g = lane >> 4, c16 = lane & 15;

  f32x4 acc[4][4];
#pragma unroll
  for (int a = 0; a < 4; ++a)
#pragma unroll
    for (int b = 0; b < 4; ++b) acc[a][b] = {0.f, 0.f, 0.f, 0.f};

  for (int kt = 0; kt < NT; ++kt) {
    const int k0 = kt * BK;
#pragma unroll
    for (int i = 0; i < 4; ++i) {
      int item = i * 256 + t;
      int row = item >> 3;
      int sub = item & 7;
      const float* src = A + (size_t)(m0 + row) * K_DIM + k0 + sub * 8;
      f32x4 v0 = *(const f32x4*)src;
      f32x4 v1 = *(const f32x4*)(src + 4);
      uint4 o;
      o.x = pack_bf16x2(v0.x, v0.y);
      o.y = pack_bf16x2(v0.z, v0.w);
      o.z = pack_bf16x2(v1.x, v1.y);
      o.w = pack_bf16x2(v1.z, v1.w);
      int chunk = sub ^ (row & 7);
      *(uint4*)&Asm[row * 64 + chunk * 8] = o;
    }
#pragma unroll
    for (int j = 0; j < 4; ++j) {
      int chunkid = w * 4 + j;
      int item = chunkid * 64 + lane;
      int row = item >> 3;
      int sub = (item & 7) ^ (row & 7);
      const unsigned short* gp = B + (size_t)(n0 + row) * K_DIM + k0 + sub * 8;
      __builtin_amdgcn_global_load_lds(
          (const __attribute__((address_space(1))) void*)gp,
          (__attribute__((address_space(3))) void*)&Bsm[chunkid * 512],
          16, 0, 0);
    }
    __syncthreads();
#pragma unroll
    for (int ks = 0; ks < 2; ++ks) {
      const int sub = ks * 4 + g;
      short8 af[4], bfr[4];
#pragma unroll
      for (int a = 0; a < 4; ++a) {
        int row = wm * 64 + a * 16 + c16;
        af[a] = *(const short8*)&Asm[row * 64 + ((sub ^ (row & 7)) * 8)];
      }
#pragma unroll
      for (int b = 0; b < 4; ++b) {
        int row = wn * 64 + b * 16 + c16;
        bfr[b] = *(const short8*)&Bsm[row * 64 + ((sub ^ (row & 7)) * 8)];
      }
#pragma unroll
      for (int a = 0; a < 4; ++a)
#pragma unroll
        for (int b = 0; b < 4; ++b)
          acc[a][b] = __builtin_amdgcn_mfma_f32_16x16x32_bf16(
              af[a], bfr[b], acc[a][b], 0, 0, 0);
    }
    __syncthreads();
  }
#pragma unroll
  for (int a = 0; a < 4; ++a) {
    float psum[4] = {0.f, 0.f, 0.f, 0.f};
#pragma unroll
    for (int b = 0; b < 4; ++b) {
      const int col = n0 + wn * 64 + b * 16 + c16;
      const float wo = wout[col];
#pragma unroll
      for (int j = 0; j < 4; ++j) {
        const int rl = wm * 64 + a * 16 + g * 4 + j;
        const int bidx = rl & 31;
        float v = acc[a][b][j] + pdec[bidx * N_DIM + col];
        psum[j] = fmaf(tanh_fast(v), wo, psum[j]);
      }
    }
#pragma unroll
    for (int j = 0; j < 4; ++j) {
      float p = psum[j];
      p += __shfl_xor(p, 1);
      p += __shfl_xor(p, 2);
      p += __shfl_xor(p, 4);
      p += __shfl_xor(p, 8);
      if (c16 == 0)
        atomicAdd(&logits[m0 + wm * 64 + a * 16 + g * 4 + j], p);
    }
  }
}

// ---- masked softmax over s per batch column; mask dtype auto-detected ----
__global__ void k_softmax(const float* __restrict__ logits,
                          const void* __restrict__ maskp,
                          float* __restrict__ weights) {
  const int b = blockIdx.x;
  const int t = threadIdx.x;
  const int lane = t & 63, wid = t >> 6;
  __shared__ float red[8];
  __shared__ int modeflags[2];

  if (t < 2) modeflags[t] = 0;
  __syncthreads();
  unsigned int w0 = ((const unsigned int*)maskp)[t];
  if (w0 == 0x3f800000u) modeflags[1] = 1;
  else if (w0 > 1u) modeflags[0] = 1;
  __syncthreads();
  const int mode = modeflags[1] ? 2 : (modeflags[0] ? 1 : 0);

  float v[8];
  float mx = -3.0e38f;
#pragma unroll
  for (int i = 0; i < 8; ++i) {
    int idx = (t + i * 256) * BATCH + b;
    float l = logits[idx];
    int mk;
    if (mode == 0) mk = ((const int*)maskp)[idx];
    else if (mode == 1) mk = ((const unsigned char*)maskp)[idx];
    else mk = (((const float*)maskp)[idx] != 0.f);
    l = mk ? l : -2.0e9f;
    v[i] = l;
    mx = fmaxf(mx, l);
  }
#pragma unroll
  for (int off = 1; off < 64; off <<= 1) mx = fmaxf(mx, __shfl_xor(mx, off));
  if (lane == 0) red[wid] = mx;
  __syncthreads();
  mx = fmaxf(fmaxf(red[0], red[1]), fmaxf(red[2], red[3]));

  float sum = 0.f;
#pragma unroll
  for (int i = 0; i < 8; ++i) {
    float e = __expf(v[i] - mx);
    v[i] = e;
    sum += e;
  }
#pragma unroll
  for (int off = 1; off < 64; off <<= 1) sum += __shfl_xor(sum, off);
  if (lane == 0) red[4 + wid] = sum;
  __syncthreads();
  sum = red[4] + red[5] + red[6] + red[7];
  float inv = 1.0f / sum;
#pragma unroll
  for (int i = 0; i < 8; ++i)
    weights[(t + i * 256) * BATCH + b] = v[i] * inv;
}

// ---- attn_response[b][e] = sum_s w[s][b] * enc_bf[s][b][e] ----
__global__ void k_response_bf(const unsigned short* __restrict__ enc_bf,
                              const float* __restrict__ weights,
                              float* __restrict__ out) {
  const int b = blockIdx.x & 31;
  const int ch = blockIdx.x >> 5;
  const int e = threadIdx.x * 4;
  float a0 = 0.f, a1 = 0.f, a2 = 0.f, a3 = 0.f;
  const int s0 = ch * (N_ENC / 16);
  for (int s = s0; s < s0 + N_ENC / 16; ++s) {
    float wv = weights[s * BATCH + b];
    ushort4 x = *(const ushort4*)(enc_bf + ((size_t)s * BATCH + b) * K_DIM + e);
    a0 = fmaf(wv, bf2f(x.x), a0);
    a1 = fmaf(wv, bf2f(x.y), a1);
    a2 = fmaf(wv, bf2f(x.z), a2);
    a3 = fmaf(wv, bf2f(x.w), a3);
  }
  atomicAdd(&out[b * K_DIM + e + 0], a0);
  atomicAdd(&out[b * K_DIM + e + 1], a1);
  atomicAdd(&out[b * K_DIM + e + 2], a2);
  atomicAdd(&out[b * K_DIM + e + 3], a3);
}

__global__ void k_response(const float* __restrict__ enc,
                           const float* __restrict__ weights,
                           float* __restrict__ out) {
  const int b = blockIdx.x & 31;
  const int ch = blockIdx.x >> 5;
  const int e = threadIdx.x * 4;
  float a0 = 0.f, a1 = 0.f, a2 = 0.f, a3 = 0.f;
  const int s0 = ch * (N_ENC / 16);
  for (int s = s0; s < s0 + N_ENC / 16; ++s) {
    float wv = weights[s * BATCH + b];
    f32x4 x = *(const f32x4*)(enc + ((size_t)s * BATCH + b) * K_DIM + e);
    a0 = fmaf(wv, x.x, a0);
    a1 = fmaf(wv, x.y, a1);
    a2 = fmaf(wv, x.z, a2);
    a3 = fmaf(wv, x.w, a3);
  }
  atomicAdd(&out[b * K_DIM + e + 0], a0);
  atomicAdd(&out[b * K_DIM + e + 1], a1);
  atomicAdd(&out[b * K_DIM + e + 2], a2);
  atomicAdd(&out[b * K_DIM + e + 3], a3);
}

extern "C" void kernel_launch(void* const* d_in, const int* in_sizes, int n_in,
                              void* d_out, int out_size, void* d_ws, size_t ws_size,
                              hipStream_t stream) {
  const float* enc   = (const float*)d_in[0];
  const void*  mask  = d_in[1];
  const float* dec   = (const float*)d_in[2];
  const float* w_enc = (const float*)d_in[3];
  const float* w_dec = (const float*)d_in[4];
  const float* w_out = (const float*)d_in[5];

  float* out_resp = (float*)d_out;                 // [32*1024]
  float* out_w    = out_resp + BATCH * K_DIM;      // [2048*32]

  const size_t enc_bf_bytes = (size_t)M_TOT * K_DIM * 2;       // 128 MiB
  const size_t need = enc_bf_bytes + 2 * 1024 * 1024 + 128 * 1024 + 256 * 1024;
  const bool pre = ws_size >= need;

  char* wsB = (char*)d_ws;
  unsigned short* enc_bf   = (unsigned short*)wsB;
  size_t off = pre ? enc_bf_bytes : 0;
  unsigned short* w_enc_bf = (unsigned short*)(wsB + off);     off += 2 * 1024 * 1024;
  float* pdec   = (float*)(wsB + off);                         off += 128 * 1024;
  float* logits = (float*)(wsB + off);

  hipMemsetAsync(logits, 0, (size_t)M_TOT * sizeof(float), stream);
  hipMemsetAsync(out_resp, 0, (size_t)BATCH * K_DIM * sizeof(float), stream);

  k_convert_bf16<<<512, 256, 0, stream>>>(w_enc, w_enc_bf, N_DIM * K_DIM / 8);
  k_proj_dec<<<N_DIM / 8, 256, 0, stream>>>(dec, w_dec, pdec);

  if (pre) {
    k_convert_bf16<<<2048, 256, 0, stream>>>(enc, enc_bf, M_TOT * (K_DIM / 8));
    k_gemm128<<<(M_TOT / 128) * (N_DIM / 128), 256, 0, stream>>>(
        enc_bf, w_enc_bf, pdec, w_out, logits);
  } else {
    k_gemm_f32<<<(M_TOT / 128) * (N_DIM / 128), 256, 0, stream>>>(
        enc, w_enc_bf, pdec, w_out, logits);
  }

  k_softmax<<<BATCH, 256, 0, stream>>>(logits, mask, out_w);

  if (pre) {
    k_response_bf<<<BATCH * 16, 256, 0, stream>>>(enc_bf, out_w, out_resp);
  } else {
    k_response<<<BATCH * 16, 256, 0, stream>>>(enc, out_w, out_resp);
  }
}